// Round 7
// baseline (332.095 us; speedup 1.0000x reference)
//
#include <hip/hip_runtime.h>
#include <hip/hip_bf16.h>

typedef __attribute__((ext_vector_type(4))) float  f32x4;
typedef __attribute__((ext_vector_type(8))) __bf16 bf16x8;
typedef __attribute__((ext_vector_type(4))) __bf16 bf16x4;

static __device__ __forceinline__ unsigned short bfbits(float x) {
    return __builtin_bit_cast(unsigned short, (__bf16)x);
}

// async 16B/lane global->LDS copy (no VGPR round-trip)
#define GLOAD_LDS16(g, l)                                                  \
    __builtin_amdgcn_global_load_lds(                                      \
        (const __attribute__((address_space(1))) unsigned int*)(g),        \
        (__attribute__((address_space(3))) unsigned int*)(l), 16, 0, 0)

// ---------------------------------------------------------------------------
// K1 (fused prep): blocks 0..255: a,b = x @ W1 halves (2 rows each);
// block 256: cc + emb=0 + ticket=0; blocks 257..288: bf16 transpose of W2/W3.
// ---------------------------------------------------------------------------
__global__ __launch_bounds__(256) void prep_all(
    const float* __restrict__ x, const float* __restrict__ q,
    const float* __restrict__ gW1, const float* __restrict__ gb1,
    const float* __restrict__ gW2, const float* __restrict__ gW3,
    float* __restrict__ a, float* __restrict__ b,
    float* __restrict__ cc, float* __restrict__ emb,
    unsigned int* __restrict__ ticket,
    unsigned short* __restrict__ w2t, unsigned short* __restrict__ w3t)
{
    const int t = threadIdx.x;
    const int bid = blockIdx.x;
    if (bid < 256) {
        __shared__ float xs[2][256];
        const int r0 = bid * 2;
        #pragma unroll
        for (int r = 0; r < 2; ++r) xs[r][t] = x[(r0 + r) * 256 + t];
        __syncthreads();
        float aa[2] = {0.f, 0.f}, bb[2] = {0.f, 0.f};
        #pragma unroll 4
        for (int d = 0; d < 256; ++d) {
            const float wa = gW1[d * 256 + t];
            const float wb = gW1[(256 + d) * 256 + t];
            #pragma unroll
            for (int r = 0; r < 2; ++r) {
                aa[r] = fmaf(xs[r][d], wa, aa[r]);
                bb[r] = fmaf(xs[r][d], wb, bb[r]);
            }
        }
        #pragma unroll
        for (int r = 0; r < 2; ++r) {
            a[(r0 + r) * 256 + t] = aa[r];
            b[(r0 + r) * 256 + t] = bb[r];
        }
    } else if (bid == 256) {
        float acc = gb1[t];
        #pragma unroll 8
        for (int d = 0; d < 256; ++d) acc = fmaf(q[d], gW1[(512 + d) * 256 + t], acc);
        cc[t] = acc;
        emb[t] = 0.f;
        if (t == 0) *ticket = 0u;
    } else {
        __shared__ unsigned short tile[64][65];
        const int bb_ = bid - 257;                 // 0..31
        const float* src = (bb_ < 16) ? gW2 : gW3;
        unsigned short* dst = (bb_ < 16) ? w2t : w3t;
        const int bidx = bb_ & 15;
        const int br = (bidx >> 2) * 64;   // k-block in src
        const int bc = (bidx & 3) * 64;    // n-block in src
        const int tr = t >> 6;             // 0..3
        const int tc = t & 63;
        #pragma unroll
        for (int rr = 0; rr < 16; ++rr) {
            const int r = tr * 16 + rr;    // local k
            tile[r][tc] = bfbits(src[(br + r) * 256 + bc + tc]);
        }
        __syncthreads();
        #pragma unroll
        for (int rr = 0; rr < 16; ++rr) {
            const int r = tr * 16 + rr;    // local n
            dst[(bc + r) * 256 + br + tc] = tile[tc][r];
        }
    }
}

// ---------------------------------------------------------------------------
// K2: fused pair-MLP, j-paired. Block b handles j0=2b, j1=2b+1 (grid 256 = 1
// block/CU, single round). 16 tiles of 32 i-rows. Per tile:
//   Phase A: [async global_load_lds stage of next ga tile] + layer-2 MFMA for
//            both j (operand-swapped: A=W2-frags in AGPR, B=h1-frags from LDS;
//            epilogue packs 4 consecutive-n bf16 -> one b64 store)
//   barrier
//   Phase B: layer-3 MFMA both j (colsums in regs) + [vmcnt(0); GEN next h1
//            from staged LDS (per-wave self-staged rows -> wave-local wait)]
//   barrier
// Last block (ticket) runs the f-MLP.
// ---------------------------------------------------------------------------
__global__ __launch_bounds__(512, 2) void rn_main(
    const float* __restrict__ ga, const float* __restrict__ gb,
    const float* __restrict__ cc,
    const unsigned short* __restrict__ w2t, const unsigned short* __restrict__ w3t,
    const float* __restrict__ gb2, const float* __restrict__ gb3,
    float* __restrict__ emb, unsigned int* __restrict__ ticket,
    const float* __restrict__ fW1, const float* __restrict__ fb1,
    const float* __restrict__ fW2, const float* __restrict__ fb2,
    const float* __restrict__ fW3, const float* __restrict__ fb3,
    float* __restrict__ out)
{
    __shared__ __bf16 h1a[32 * 256], h1b[32 * 256];   // 16KB each
    __shared__ __bf16 h2a[32 * 256], h2b[32 * 256];   // 16KB each
    __shared__ float gstage[32 * 256];                // 32KB staged ga tile
    __shared__ float fe[256], fy1[256], fy2[512], fred[512];
    __shared__ int is_last_s;

    const int t = threadIdx.x;
    const int j0 = blockIdx.x * 2;
    const int lane = t & 63;
    const int wave = t >> 6;           // 0..7
    const int l16 = lane & 15;
    const int lk = lane >> 4;          // 0..3
    const int wcol = wave * 32;        // this wave's 32 output-col slice

    // ---- bc = b[j] + cc for both j, in registers ----
    const int k0 = (t & 31) << 3;
    f32x4 bca0, bca1, bcb0, bcb1;
    {
        const f32x4 c0 = *reinterpret_cast<const f32x4*>(cc + k0);
        const f32x4 c1 = *reinterpret_cast<const f32x4*>(cc + k0 + 4);
        const f32x4 ga0 = *reinterpret_cast<const f32x4*>(gb + j0 * 256 + k0);
        const f32x4 ga1 = *reinterpret_cast<const f32x4*>(gb + j0 * 256 + k0 + 4);
        const f32x4 gb0 = *reinterpret_cast<const f32x4*>(gb + (j0 + 1) * 256 + k0);
        const f32x4 gb1v = *reinterpret_cast<const f32x4*>(gb + (j0 + 1) * 256 + k0 + 4);
        #pragma unroll
        for (int e = 0; e < 4; ++e) {
            bca0[e] = ga0[e] + c0[e];  bca1[e] = ga1[e] + c1[e];
            bcb0[e] = gb0[e] + c0[e];  bcb1[e] = gb1v[e] + c1[e];
        }
    }

    // ---- register/AGPR-resident weight fragments (A-operand rows = cols n) ----
    bf16x8 B2[2][8], B3[2][8];
    float bias2r[2][4], bias3r[2][4];
    #pragma unroll
    for (int ns = 0; ns < 2; ++ns) {
        #pragma unroll
        for (int reg = 0; reg < 4; ++reg) {
            const int n = wcol + ns * 16 + lk * 4 + reg;
            bias2r[ns][reg] = gb2[n];
            bias3r[ns][reg] = gb3[n];
        }
        const int colA = wcol + ns * 16 + l16;
        #pragma unroll
        for (int ks = 0; ks < 8; ++ks) {
            const int koff = ks * 32 + lk * 8;
            B2[ns][ks] = *reinterpret_cast<const bf16x8*>(w2t + colA * 256 + koff);
            B3[ns][ks] = *reinterpret_cast<const bf16x8*>(w3t + colA * 256 + koff);
        }
    }
    float cs[2][2][4];
    #pragma unroll
    for (int jj = 0; jj < 2; ++jj)
        #pragma unroll
        for (int ns = 0; ns < 2; ++ns)
            #pragma unroll
            for (int reg = 0; reg < 4; ++reg) cs[jj][ns][reg] = 0.f;

    // wave w stages + GENs rows {2w, 2w+1, 2w+16, 2w+17} of each 32-row tile
    #define STAGE(IT)                                                              \
    {                                                                              \
        const int rb = (IT) * 32;                                                  \
        _Pragma("unroll")                                                          \
        for (int i = 0; i < 4; ++i) {                                              \
            const int row = 2 * wave + (i & 1) + (i >> 1) * 16;                    \
            GLOAD_LDS16(ga + (rb + row) * 256 + lane * 4, &gstage[row * 256]);     \
        }                                                                          \
    }

    #define GEN()                                                                  \
    {                                                                              \
        _Pragma("unroll")                                                          \
        for (int r = 0; r < 2; ++r) {                                              \
            const int m = (t >> 5) + r * 16;                                       \
            const f32x4 g0 = *reinterpret_cast<const f32x4*>(&gstage[m * 256 + k0]);       \
            const f32x4 g1 = *reinterpret_cast<const f32x4*>(&gstage[m * 256 + k0 + 4]);   \
            bf16x8 pa, pb;                                                         \
            _Pragma("unroll")                                                      \
            for (int e = 0; e < 4; ++e) {                                          \
                pa[e]     = (__bf16)fmaxf(g0[e] + bca0[e], 0.f);                   \
                pa[e + 4] = (__bf16)fmaxf(g1[e] + bca1[e], 0.f);                   \
                pb[e]     = (__bf16)fmaxf(g0[e] + bcb0[e], 0.f);                   \
                pb[e + 4] = (__bf16)fmaxf(g1[e] + bcb1[e], 0.f);                   \
            }                                                                      \
            const int off = (m * 256 + k0) ^ ((m & 7) << 3);                       \
            *reinterpret_cast<bf16x8*>(&h1a[off]) = pa;                            \
            *reinterpret_cast<bf16x8*>(&h1b[off]) = pb;                            \
        }                                                                          \
    }

    // layer 2 (swapped): D[n][m] = sum_k W2t[n][k] * H1[m][k]
    #define L2(H1, H2)                                                             \
    {                                                                              \
        _Pragma("unroll")                                                          \
        for (int mt = 0; mt < 2; ++mt) {                                           \
            const int m = mt * 16 + l16;                                           \
            bf16x8 F[8];                                                           \
            _Pragma("unroll")                                                      \
            for (int ks = 0; ks < 8; ++ks)                                         \
                F[ks] = *reinterpret_cast<const bf16x8*>(                          \
                    &(H1)[(m * 256 + ks * 32 + lk * 8) ^ ((m & 7) << 3)]);         \
            _Pragma("unroll")                                                      \
            for (int ns = 0; ns < 2; ++ns) {                                       \
                f32x4 acc = {0.f, 0.f, 0.f, 0.f};                                  \
                _Pragma("unroll")                                                  \
                for (int ks = 0; ks < 8; ++ks)                                     \
                    acc = __builtin_amdgcn_mfma_f32_16x16x32_bf16(                 \
                        B2[ns][ks], F[ks], acc, 0, 0, 0);                          \
                bf16x4 pk;                                                         \
                _Pragma("unroll")                                                  \
                for (int reg = 0; reg < 4; ++reg)                                  \
                    pk[reg] = (__bf16)fmaxf(acc[reg] + bias2r[ns][reg], 0.f);      \
                *reinterpret_cast<bf16x4*>(                                        \
                    &(H2)[(m * 256 + wcol + ns * 16 + lk * 4) ^ ((m & 7) << 3)]) = pk; \
            }                                                                      \
        }                                                                          \
    }

    // layer 3 (swapped): colsum accumulate, no store
    #define L3(H2, JJ)                                                             \
    {                                                                              \
        _Pragma("unroll")                                                          \
        for (int mt = 0; mt < 2; ++mt) {                                           \
            const int m = mt * 16 + l16;                                           \
            bf16x8 G[8];                                                           \
            _Pragma("unroll")                                                      \
            for (int ks = 0; ks < 8; ++ks)                                         \
                G[ks] = *reinterpret_cast<const bf16x8*>(                          \
                    &(H2)[(m * 256 + ks * 32 + lk * 8) ^ ((m & 7) << 3)]);         \
            _Pragma("unroll")                                                      \
            for (int ns = 0; ns < 2; ++ns) {                                       \
                f32x4 acc = {0.f, 0.f, 0.f, 0.f};                                  \
                _Pragma("unroll")                                                  \
                for (int ks = 0; ks < 8; ++ks)                                     \
                    acc = __builtin_amdgcn_mfma_f32_16x16x32_bf16(                 \
                        B3[ns][ks], G[ks], acc, 0, 0, 0);                          \
                _Pragma("unroll")                                                  \
                for (int reg = 0; reg < 4; ++reg)                                  \
                    cs[JJ][ns][reg] += fmaxf(acc[reg] + bias3r[ns][reg], 0.f);     \
            }                                                                      \
        }                                                                          \
    }

    // ---- prologue: stage tile 0, wave-local wait, GEN h1 tile 0 ----
    STAGE(0);
    asm volatile("s_waitcnt vmcnt(0)" ::: "memory");
    GEN();
    __syncthreads();

    for (int it = 0; it < 16; ++it) {
        if (it < 15) STAGE(it + 1);
        __builtin_amdgcn_sched_barrier(0);
        L2(h1a, h2a);
        L2(h1b, h2b);
        __syncthreads();   // h2 ready; all h1 reads done
        L3(h2a, 0);
        L3(h2b, 1);
        if (it < 15) {
            asm volatile("s_waitcnt vmcnt(0)" ::: "memory");
            GEN();
        }
        __syncthreads();   // h2 consumed + h1(next) ready + gstage reusable
    }

    // ---- reduce colsums over the 16 m-slots (l16) and atomically add ----
    #pragma unroll
    for (int ns = 0; ns < 2; ++ns)
        #pragma unroll
        for (int reg = 0; reg < 4; ++reg) {
            float v = cs[0][ns][reg] + cs[1][ns][reg];
            v += __shfl_xor(v, 1, 64);
            v += __shfl_xor(v, 2, 64);
            v += __shfl_xor(v, 4, 64);
            v += __shfl_xor(v, 8, 64);
            if (l16 == 0) atomicAdd(&emb[wcol + ns * 16 + lk * 4 + reg], v);
        }

    // ---- last-block ticket: the final block runs the f-MLP ----
    __syncthreads();
    if (t == 0) {
        __threadfence();
        const unsigned int done = atomicAdd(ticket, 1u);
        is_last_s = (done == 255u);
    }
    __syncthreads();
    if (!is_last_s) return;

    __threadfence();   // acquire: make all blocks' emb atomics visible
    if (t < 256) fe[t] = emb[t];
    __syncthreads();
    // f1: 256 cols x 2-way k-split (128 each)
    {
        const int col = t & 255, ks = t >> 8;
        float acc = 0.f;
        #pragma unroll 8
        for (int k = ks * 128; k < ks * 128 + 128; ++k) acc = fmaf(fe[k], fW1[k * 256 + col], acc);
        fred[ks * 256 + col] = acc;
    }
    __syncthreads();
    if (t < 256) fy1[t] = fmaxf(fred[t] + fred[256 + t] + fb1[t], 0.f);
    __syncthreads();
    // f2: 512 cols x 1 thread each
    {
        float acc = fb2[t];
        #pragma unroll 8
        for (int k = 0; k < 256; ++k) acc = fmaf(fy1[k], fW2[k * 512 + t], acc);
        fy2[t] = fmaxf(acc, 0.f);
    }
    __syncthreads();
    // f3: 159 cols x 2-way k-split (256 each)
    {
        const int col = t & 255, ks = t >> 8;
        if (col < 159) {
            float acc = 0.f;
            #pragma unroll 8
            for (int k = ks * 256; k < ks * 256 + 256; ++k) acc = fmaf(fy2[k], fW3[k * 159 + col], acc);
            fred[ks * 256 + col] = acc;
        }
    }
    __syncthreads();
    if (t < 159) out[t] = fred[t] + fred[256 + t] + fb3[t];

    #undef STAGE
    #undef GEN
    #undef L2
    #undef L3
}

// ---------------------------------------------------------------------------
extern "C" void kernel_launch(void* const* d_in, const int* in_sizes, int n_in,
                              void* d_out, int out_size, void* d_ws, size_t ws_size,
                              hipStream_t stream)
{
    const float* x   = (const float*)d_in[0];
    const float* q   = (const float*)d_in[1];
    const float* gW1 = (const float*)d_in[2];
    const float* gb1 = (const float*)d_in[3];
    const float* gW2 = (const float*)d_in[4];
    const float* gb2 = (const float*)d_in[5];
    const float* gW3 = (const float*)d_in[6];
    const float* gb3 = (const float*)d_in[7];
    const float* fW1 = (const float*)d_in[8];
    const float* fb1 = (const float*)d_in[9];
    const float* fW2 = (const float*)d_in[10];
    const float* fb2 = (const float*)d_in[11];
    const float* fW3 = (const float*)d_in[12];
    const float* fb3 = (const float*)d_in[13];
    float* out = (float*)d_out;

    char* ws = (char*)d_ws;
    float* a_  = (float*)(ws);                                  // 512KB
    float* b_  = (float*)(ws + 512 * 1024);                     // 512KB
    float* cc  = (float*)(ws + 1024 * 1024);                    // 1KB
    float* emb = (float*)(ws + 1024 * 1024 + 1024);             // 1KB
    unsigned int* ticket = (unsigned int*)(ws + 1024 * 1024 + 2048);
    unsigned short* w2t = (unsigned short*)(ws + 1024 * 1024 + 4096);              // 128KB
    unsigned short* w3t = (unsigned short*)(ws + 1024 * 1024 + 4096 + 128 * 1024); // 128KB

    prep_all<<<289, 256, 0, stream>>>(x, q, gW1, gb1, gW2, gW3, a_, b_, cc, emb,
                                      ticket, w2t, w3t);
    rn_main<<<256, 512, 0, stream>>>(a_, b_, cc, w2t, w3t, gb2, gb3, emb, ticket,
                                     fW1, fb1, fW2, fb2, fW3, fb3, out);
}

// Round 8
// 278.027 us; speedup vs baseline: 1.1945x; 1.1945x over previous
//
#include <hip/hip_runtime.h>
#include <hip/hip_bf16.h>

typedef __attribute__((ext_vector_type(4))) float  f32x4;
typedef __attribute__((ext_vector_type(8))) __bf16 bf16x8;
typedef __attribute__((ext_vector_type(4))) __bf16 bf16x4;

static __device__ __forceinline__ unsigned short bfbits(float x) {
    return __builtin_bit_cast(unsigned short, (__bf16)x);
}

// async 16B/lane global->LDS copy (no VGPR round-trip)
#define GLOAD_LDS16(g, l)                                                  \
    __builtin_amdgcn_global_load_lds(                                      \
        (const __attribute__((address_space(1))) unsigned int*)(g),        \
        (__attribute__((address_space(3))) unsigned int*)(l), 16, 0, 0)

// ---------------------------------------------------------------------------
// K1 (fused prep): blocks 0..255: a,b = x @ W1 halves (2 rows each);
// block 256: cc + emb=0 + ticket=0; blocks 257..288: bf16 transpose of W2/W3.
// ---------------------------------------------------------------------------
__global__ __launch_bounds__(256) void prep_all(
    const float* __restrict__ x, const float* __restrict__ q,
    const float* __restrict__ gW1, const float* __restrict__ gb1,
    const float* __restrict__ gW2, const float* __restrict__ gW3,
    float* __restrict__ a, float* __restrict__ b,
    float* __restrict__ cc, float* __restrict__ emb,
    unsigned int* __restrict__ ticket,
    unsigned short* __restrict__ w2t, unsigned short* __restrict__ w3t)
{
    const int t = threadIdx.x;
    const int bid = blockIdx.x;
    if (bid < 256) {
        __shared__ float xs[2][256];
        const int r0 = bid * 2;
        #pragma unroll
        for (int r = 0; r < 2; ++r) xs[r][t] = x[(r0 + r) * 256 + t];
        __syncthreads();
        float aa[2] = {0.f, 0.f}, bb[2] = {0.f, 0.f};
        #pragma unroll 4
        for (int d = 0; d < 256; ++d) {
            const float wa = gW1[d * 256 + t];
            const float wb = gW1[(256 + d) * 256 + t];
            #pragma unroll
            for (int r = 0; r < 2; ++r) {
                aa[r] = fmaf(xs[r][d], wa, aa[r]);
                bb[r] = fmaf(xs[r][d], wb, bb[r]);
            }
        }
        #pragma unroll
        for (int r = 0; r < 2; ++r) {
            a[(r0 + r) * 256 + t] = aa[r];
            b[(r0 + r) * 256 + t] = bb[r];
        }
    } else if (bid == 256) {
        float acc = gb1[t];
        #pragma unroll 8
        for (int d = 0; d < 256; ++d) acc = fmaf(q[d], gW1[(512 + d) * 256 + t], acc);
        cc[t] = acc;
        emb[t] = 0.f;
        if (t == 0) *ticket = 0u;
    } else {
        __shared__ unsigned short tile[64][65];
        const int bb_ = bid - 257;                 // 0..31
        const float* src = (bb_ < 16) ? gW2 : gW3;
        unsigned short* dst = (bb_ < 16) ? w2t : w3t;
        const int bidx = bb_ & 15;
        const int br = (bidx >> 2) * 64;   // k-block in src
        const int bc = (bidx & 3) * 64;    // n-block in src
        const int tr = t >> 6;             // 0..3
        const int tc = t & 63;
        #pragma unroll
        for (int rr = 0; rr < 16; ++rr) {
            const int r = tr * 16 + rr;    // local k
            tile[r][tc] = bfbits(src[(br + r) * 256 + bc + tc]);
        }
        __syncthreads();
        #pragma unroll
        for (int rr = 0; rr < 16; ++rr) {
            const int r = tr * 16 + rr;    // local n
            dst[(bc + r) * 256 + br + tc] = tile[tc][r];
        }
    }
}

// ---------------------------------------------------------------------------
// K2: fused pair-MLP, sequential j-passes. Block b runs j = 2b then 2b+1
// (grid 256 = 1 block/CU, single round). Per pass: 8 tiles of 64 i-rows.
// Per tile: [async stage next ga tile] Phase A = layer-2 MFMA (swapped:
// A=W-frags in regs/AGPR, B=h1 from LDS; b64 epilogue stores); barrier;
// Phase B = layer-3 MFMA (colsums in regs) + [vmcnt(0); GEN next h1 from
// staged LDS, wave-local]. Lean registers: ~200 peak (no spill).
// Last block (ticket) runs the f-MLP.
// ---------------------------------------------------------------------------
__global__ __launch_bounds__(512, 2) void rn_main(
    const float* __restrict__ ga, const float* __restrict__ gb,
    const float* __restrict__ cc,
    const unsigned short* __restrict__ w2t, const unsigned short* __restrict__ w3t,
    const float* __restrict__ gb2, const float* __restrict__ gb3,
    float* __restrict__ emb, unsigned int* __restrict__ ticket,
    const float* __restrict__ fW1, const float* __restrict__ fb1,
    const float* __restrict__ fW2, const float* __restrict__ fb2,
    const float* __restrict__ fW3, const float* __restrict__ fb3,
    float* __restrict__ out)
{
    __shared__ float gstage[64 * 256];     // 64KB staged ga tile (f32)
    __shared__ __bf16 h1[64 * 256];        // 32KB
    __shared__ __bf16 h2[64 * 256];        // 32KB
    __shared__ float fe[256], fy1[256], fy2[512], fred[512];
    __shared__ int is_last_s;

    const int t = threadIdx.x;
    const int j0 = blockIdx.x * 2;
    const int lane = t & 63;
    const int wave = t >> 6;           // 0..7
    const int l16 = lane & 15;
    const int lk = lane >> 4;          // 0..3
    const int wcol = wave * 32;        // this wave's 32 output-col slice
    const int k0 = (t & 31) << 3;      // h1-gen k-slice

    // ---- register/AGPR-resident weight fragments (A-operand rows = cols n) ----
    bf16x8 B2[2][8], B3[2][8];
    float bias2r[2][4], bias3r[2][4];
    #pragma unroll
    for (int ns = 0; ns < 2; ++ns) {
        #pragma unroll
        for (int reg = 0; reg < 4; ++reg) {
            const int n = wcol + ns * 16 + lk * 4 + reg;
            bias2r[ns][reg] = gb2[n];
            bias3r[ns][reg] = gb3[n];
        }
        const int colA = wcol + ns * 16 + l16;
        #pragma unroll
        for (int ks = 0; ks < 8; ++ks) {
            const int koff = ks * 32 + lk * 8;
            B2[ns][ks] = *reinterpret_cast<const bf16x8*>(w2t + colA * 256 + koff);
            B3[ns][ks] = *reinterpret_cast<const bf16x8*>(w3t + colA * 256 + koff);
        }
    }
    float cs[2][4];
    #pragma unroll
    for (int ns = 0; ns < 2; ++ns)
        #pragma unroll
        for (int reg = 0; reg < 4; ++reg) cs[ns][reg] = 0.f;

    // wave w stages + GENs rows {2w+(0|1) + 16*(0..3)} of each 64-row tile
    #define STAGE(IT)                                                              \
    {                                                                              \
        const int rb = (IT) * 64;                                                  \
        _Pragma("unroll")                                                          \
        for (int i = 0; i < 8; ++i) {                                              \
            const int row = 2 * wave + (i & 1) + (i >> 1) * 16;                    \
            GLOAD_LDS16(ga + (rb + row) * 256 + lane * 4, &gstage[row * 256]);     \
        }                                                                          \
    }

    #define GEN()                                                                  \
    {                                                                              \
        _Pragma("unroll")                                                          \
        for (int r = 0; r < 4; ++r) {                                              \
            const int m = (t >> 5) + r * 16;                                       \
            const f32x4 g0 = *reinterpret_cast<const f32x4*>(&gstage[m * 256 + k0]);       \
            const f32x4 g1 = *reinterpret_cast<const f32x4*>(&gstage[m * 256 + k0 + 4]);   \
            bf16x8 pa;                                                             \
            _Pragma("unroll")                                                      \
            for (int e = 0; e < 4; ++e) {                                          \
                pa[e]     = (__bf16)fmaxf(g0[e] + bc0[e], 0.f);                    \
                pa[e + 4] = (__bf16)fmaxf(g1[e] + bc1[e], 0.f);                    \
            }                                                                      \
            *reinterpret_cast<bf16x8*>(&h1[(m * 256 + k0) ^ ((m & 7) << 3)]) = pa; \
        }                                                                          \
    }

    // layer 2 (swapped): D[n][m] = sum_k W2t[n][k] * H1[m][k]
    #define L2()                                                                   \
    {                                                                              \
        _Pragma("unroll")                                                          \
        for (int mt = 0; mt < 4; ++mt) {                                           \
            const int m = mt * 16 + l16;                                           \
            bf16x8 F[8];                                                           \
            _Pragma("unroll")                                                      \
            for (int ks = 0; ks < 8; ++ks)                                         \
                F[ks] = *reinterpret_cast<const bf16x8*>(                          \
                    &h1[(m * 256 + ks * 32 + lk * 8) ^ ((m & 7) << 3)]);           \
            _Pragma("unroll")                                                      \
            for (int ns = 0; ns < 2; ++ns) {                                       \
                f32x4 acc = {0.f, 0.f, 0.f, 0.f};                                  \
                _Pragma("unroll")                                                  \
                for (int ks = 0; ks < 8; ++ks)                                     \
                    acc = __builtin_amdgcn_mfma_f32_16x16x32_bf16(                 \
                        B2[ns][ks], F[ks], acc, 0, 0, 0);                          \
                bf16x4 pk;                                                         \
                _Pragma("unroll")                                                  \
                for (int reg = 0; reg < 4; ++reg)                                  \
                    pk[reg] = (__bf16)fmaxf(acc[reg] + bias2r[ns][reg], 0.f);      \
                *reinterpret_cast<bf16x4*>(                                        \
                    &h2[(m * 256 + wcol + ns * 16 + lk * 4) ^ ((m & 7) << 3)]) = pk; \
            }                                                                      \
        }                                                                          \
    }

    // layer 3 (swapped): colsum accumulate, no store
    #define L3()                                                                   \
    {                                                                              \
        _Pragma("unroll")                                                          \
        for (int mt = 0; mt < 4; ++mt) {                                           \
            const int m = mt * 16 + l16;                                           \
            bf16x8 G[8];                                                           \
            _Pragma("unroll")                                                      \
            for (int ks = 0; ks < 8; ++ks)                                         \
                G[ks] = *reinterpret_cast<const bf16x8*>(                          \
                    &h2[(m * 256 + ks * 32 + lk * 8) ^ ((m & 7) << 3)]);           \
            _Pragma("unroll")                                                      \
            for (int ns = 0; ns < 2; ++ns) {                                       \
                f32x4 acc = {0.f, 0.f, 0.f, 0.f};                                  \
                _Pragma("unroll")                                                  \
                for (int ks = 0; ks < 8; ++ks)                                     \
                    acc = __builtin_amdgcn_mfma_f32_16x16x32_bf16(                 \
                        B3[ns][ks], G[ks], acc, 0, 0, 0);                          \
                _Pragma("unroll")                                                  \
                for (int reg = 0; reg < 4; ++reg)                                  \
                    cs[ns][reg] += fmaxf(acc[reg] + bias3r[ns][reg], 0.f);         \
            }                                                                      \
        }                                                                          \
    }

    #pragma unroll 1
    for (int jj = 0; jj < 2; ++jj) {
        const int j = j0 + jj;
        // ---- bc = b[j] + cc, in registers ----
        f32x4 bc0, bc1;
        {
            const f32x4 c0 = *reinterpret_cast<const f32x4*>(cc + k0);
            const f32x4 c1 = *reinterpret_cast<const f32x4*>(cc + k0 + 4);
            const f32x4 g0 = *reinterpret_cast<const f32x4*>(gb + j * 256 + k0);
            const f32x4 g1 = *reinterpret_cast<const f32x4*>(gb + j * 256 + k0 + 4);
            #pragma unroll
            for (int e = 0; e < 4; ++e) { bc0[e] = g0[e] + c0[e]; bc1[e] = g1[e] + c1[e]; }
        }

        // ---- pass prologue: stage tile 0, wave-local wait, GEN h1 tile 0 ----
        STAGE(0);
        asm volatile("s_waitcnt vmcnt(0)" ::: "memory");
        GEN();
        __syncthreads();

        #pragma unroll 1
        for (int it = 0; it < 8; ++it) {
            if (it < 7) STAGE(it + 1);
            __builtin_amdgcn_sched_barrier(0);
            L2();
            __syncthreads();   // h2 ready; all h1 reads done
            L3();
            if (it < 7) {
                asm volatile("s_waitcnt vmcnt(0)" ::: "memory");
                GEN();
            }
            __syncthreads();   // h2 consumed + h1(next) ready + gstage reusable
        }
    }

    // ---- reduce colsums over the 16 m-slots (l16) and atomically add ----
    #pragma unroll
    for (int ns = 0; ns < 2; ++ns)
        #pragma unroll
        for (int reg = 0; reg < 4; ++reg) {
            float v = cs[ns][reg];
            v += __shfl_xor(v, 1, 64);
            v += __shfl_xor(v, 2, 64);
            v += __shfl_xor(v, 4, 64);
            v += __shfl_xor(v, 8, 64);
            if (l16 == 0) atomicAdd(&emb[wcol + ns * 16 + lk * 4 + reg], v);
        }

    // ---- last-block ticket: the final block runs the f-MLP ----
    __syncthreads();
    if (t == 0) {
        __threadfence();
        const unsigned int done = atomicAdd(ticket, 1u);
        is_last_s = (done == 255u);
    }
    __syncthreads();
    if (!is_last_s) return;

    __threadfence();   // acquire: make all blocks' emb atomics visible
    if (t < 256) fe[t] = emb[t];
    __syncthreads();
    // f1: 256 cols x 2-way k-split (128 each)
    {
        const int col = t & 255, ks = t >> 8;
        float acc = 0.f;
        #pragma unroll 8
        for (int k = ks * 128; k < ks * 128 + 128; ++k) acc = fmaf(fe[k], fW1[k * 256 + col], acc);
        fred[ks * 256 + col] = acc;
    }
    __syncthreads();
    if (t < 256) fy1[t] = fmaxf(fred[t] + fred[256 + t] + fb1[t], 0.f);
    __syncthreads();
    // f2: 512 cols x 1 thread each
    {
        float acc = fb2[t];
        #pragma unroll 8
        for (int k = 0; k < 256; ++k) acc = fmaf(fy1[k], fW2[k * 512 + t], acc);
        fy2[t] = fmaxf(acc, 0.f);
    }
    __syncthreads();
    // f3: 159 cols x 2-way k-split (256 each)
    {
        const int col = t & 255, ks = t >> 8;
        if (col < 159) {
            float acc = 0.f;
            #pragma unroll 8
            for (int k = ks * 256; k < ks * 256 + 256; ++k) acc = fmaf(fy2[k], fW3[k * 159 + col], acc);
            fred[ks * 256 + col] = acc;
        }
    }
    __syncthreads();
    if (t < 159) out[t] = fred[t] + fred[256 + t] + fb3[t];

    #undef STAGE
    #undef GEN
    #undef L2
    #undef L3
}

// ---------------------------------------------------------------------------
extern "C" void kernel_launch(void* const* d_in, const int* in_sizes, int n_in,
                              void* d_out, int out_size, void* d_ws, size_t ws_size,
                              hipStream_t stream)
{
    const float* x   = (const float*)d_in[0];
    const float* q   = (const float*)d_in[1];
    const float* gW1 = (const float*)d_in[2];
    const float* gb1 = (const float*)d_in[3];
    const float* gW2 = (const float*)d_in[4];
    const float* gb2 = (const float*)d_in[5];
    const float* gW3 = (const float*)d_in[6];
    const float* gb3 = (const float*)d_in[7];
    const float* fW1 = (const float*)d_in[8];
    const float* fb1 = (const float*)d_in[9];
    const float* fW2 = (const float*)d_in[10];
    const float* fb2 = (const float*)d_in[11];
    const float* fW3 = (const float*)d_in[12];
    const float* fb3 = (const float*)d_in[13];
    float* out = (float*)d_out;

    char* ws = (char*)d_ws;
    float* a_  = (float*)(ws);                                  // 512KB
    float* b_  = (float*)(ws + 512 * 1024);                     // 512KB
    float* cc  = (float*)(ws + 1024 * 1024);                    // 1KB
    float* emb = (float*)(ws + 1024 * 1024 + 1024);             // 1KB
    unsigned int* ticket = (unsigned int*)(ws + 1024 * 1024 + 2048);
    unsigned short* w2t = (unsigned short*)(ws + 1024 * 1024 + 4096);              // 128KB
    unsigned short* w3t = (unsigned short*)(ws + 1024 * 1024 + 4096 + 128 * 1024); // 128KB

    prep_all<<<289, 256, 0, stream>>>(x, q, gW1, gb1, gW2, gW3, a_, b_, cc, emb,
                                      ticket, w2t, w3t);
    rn_main<<<256, 512, 0, stream>>>(a_, b_, cc, w2t, w3t, gb2, gb3, emb, ticket,
                                     fW1, fb1, fW2, fb2, fW3, fb3, out);
}

// Round 9
// 223.527 us; speedup vs baseline: 1.4857x; 1.2438x over previous
//
#include <hip/hip_runtime.h>
#include <hip/hip_bf16.h>

typedef __attribute__((ext_vector_type(4))) float  f32x4;
typedef __attribute__((ext_vector_type(8))) __bf16 bf16x8;

static __device__ __forceinline__ unsigned short bfbits(float x) {
    return __builtin_bit_cast(unsigned short, (__bf16)x);
}

// ---------------------------------------------------------------------------
// K1 (fused prep): blocks 0..255: a,b = x @ W1 halves (2 rows each);
// block 256: cc + emb=0 + ticket=0; blocks 257..288: bf16 transpose of W2/W3.
// ---------------------------------------------------------------------------
__global__ __launch_bounds__(256) void prep_all(
    const float* __restrict__ x, const float* __restrict__ q,
    const float* __restrict__ gW1, const float* __restrict__ gb1,
    const float* __restrict__ gW2, const float* __restrict__ gW3,
    float* __restrict__ a, float* __restrict__ b,
    float* __restrict__ cc, float* __restrict__ emb,
    unsigned int* __restrict__ ticket,
    unsigned short* __restrict__ w2t, unsigned short* __restrict__ w3t)
{
    const int t = threadIdx.x;
    const int bid = blockIdx.x;
    if (bid < 256) {
        __shared__ float xs[2][256];
        const int r0 = bid * 2;
        #pragma unroll
        for (int r = 0; r < 2; ++r) xs[r][t] = x[(r0 + r) * 256 + t];
        __syncthreads();
        float aa[2] = {0.f, 0.f}, bb[2] = {0.f, 0.f};
        #pragma unroll 4
        for (int d = 0; d < 256; ++d) {
            const float wa = gW1[d * 256 + t];
            const float wb = gW1[(256 + d) * 256 + t];
            #pragma unroll
            for (int r = 0; r < 2; ++r) {
                aa[r] = fmaf(xs[r][d], wa, aa[r]);
                bb[r] = fmaf(xs[r][d], wb, bb[r]);
            }
        }
        #pragma unroll
        for (int r = 0; r < 2; ++r) {
            a[(r0 + r) * 256 + t] = aa[r];
            b[(r0 + r) * 256 + t] = bb[r];
        }
    } else if (bid == 256) {
        float acc = gb1[t];
        #pragma unroll 8
        for (int d = 0; d < 256; ++d) acc = fmaf(q[d], gW1[(512 + d) * 256 + t], acc);
        cc[t] = acc;
        emb[t] = 0.f;
        if (t == 0) *ticket = 0u;
    } else {
        __shared__ unsigned short tile[64][65];
        const int bb_ = bid - 257;                 // 0..31
        const float* src = (bb_ < 16) ? gW2 : gW3;
        unsigned short* dst = (bb_ < 16) ? w2t : w3t;
        const int bidx = bb_ & 15;
        const int br = (bidx >> 2) * 64;   // k-block in src
        const int bc = (bidx & 3) * 64;    // n-block in src
        const int tr = t >> 6;             // 0..3
        const int tc = t & 63;
        #pragma unroll
        for (int rr = 0; rr < 16; ++rr) {
            const int r = tr * 16 + rr;    // local k
            tile[r][tc] = bfbits(src[(br + r) * 256 + bc + tc]);
        }
        __syncthreads();
        #pragma unroll
        for (int rr = 0; rr < 16; ++rr) {
            const int r = tr * 16 + rr;    // local n
            dst[(bc + r) * 256 + br + tc] = tile[tc][r];
        }
    }
}

// ---------------------------------------------------------------------------
// K2: main fused pair-MLP — VERBATIM round-3 loop structure (the only
// measured spill-free register shape: 112 VGPR + 128 AGPR, 99us), plus a
// ticket-gated f-MLP tail (post-loop, non-overlapping live ranges).
// One block per j (512 blocks, 8 waves). Per 32-i tile:
// GEN h1=relu(a_i+bc) -> LDS bf16 (xor-swizzled); L2 MFMA; L3 MFMA+colsum.
// ---------------------------------------------------------------------------
__global__ __launch_bounds__(512, 2) void rn_main(
    const float* __restrict__ ga, const float* __restrict__ gb,
    const float* __restrict__ cc,
    const unsigned short* __restrict__ w2t, const unsigned short* __restrict__ w3t,
    const float* __restrict__ gb2, const float* __restrict__ gb3,
    float* __restrict__ emb, unsigned int* __restrict__ ticket,
    const float* __restrict__ fW1, const float* __restrict__ fb1,
    const float* __restrict__ fW2, const float* __restrict__ fb2,
    const float* __restrict__ fW3, const float* __restrict__ fb3,
    float* __restrict__ out)
{
    __shared__ float bc_s[256];
    __shared__ __bf16 h1[32 * 256];    // 16KB
    __shared__ __bf16 h2[32 * 256];    // 16KB
    __shared__ float fe[256], fy1[256], fy2[512], fred[512];
    __shared__ int is_last_s;

    const int t = threadIdx.x;
    const int j = blockIdx.x;
    const int lane = t & 63;
    const int wave = t >> 6;           // 0..7
    const int l16 = lane & 15;
    const int lk = lane >> 4;          // 0..3 (k-group of 8)
    const int wcol = wave * 32;        // this wave's 32-col slice

    if (t < 256) bc_s[t] = gb[j * 256 + t] + cc[t];

    // register/AGPR-resident B fragments (bf16), both layers
    bf16x8 B2[2][8], B3[2][8];
    float bias2[2], bias3[2];
    #pragma unroll
    for (int ns = 0; ns < 2; ++ns) {
        const int col = wcol + ns * 16 + l16;
        bias2[ns] = gb2[col];
        bias3[ns] = gb3[col];
        #pragma unroll
        for (int ks = 0; ks < 8; ++ks) {
            const int koff = ks * 32 + lk * 8;
            B2[ns][ks] = *reinterpret_cast<const bf16x8*>(w2t + col * 256 + koff);
            B3[ns][ks] = *reinterpret_cast<const bf16x8*>(w3t + col * 256 + koff);
        }
    }
    float colsum[2] = {0.f, 0.f};
    __syncthreads();   // bc_s ready

    #pragma unroll 1
    for (int it = 0; it < 16; ++it) {
        const int i0 = it * 32;
        // ---- h1 = relu(a_i + bc) -> bf16 LDS (swizzled) ----
        #pragma unroll
        for (int r = 0; r < 2; ++r) {
            const int idx = t + r * 512;        // 0..1023
            const int m = idx >> 5;             // 0..31
            const int k0 = (idx & 31) << 3;     // 0..248
            const f32x4 a0 = *reinterpret_cast<const f32x4*>(ga + (i0 + m) * 256 + k0);
            const f32x4 a1 = *reinterpret_cast<const f32x4*>(ga + (i0 + m) * 256 + k0 + 4);
            const f32x4 c0 = *reinterpret_cast<const f32x4*>(bc_s + k0);
            const f32x4 c1 = *reinterpret_cast<const f32x4*>(bc_s + k0 + 4);
            bf16x8 pk;
            #pragma unroll
            for (int e = 0; e < 4; ++e) {
                pk[e]     = (__bf16)fmaxf(a0[e] + c0[e], 0.f);
                pk[e + 4] = (__bf16)fmaxf(a1[e] + c1[e], 0.f);
            }
            *reinterpret_cast<bf16x8*>(&h1[(m * 256 + k0) ^ ((m & 7) << 3)]) = pk;
        }
        __syncthreads();   // h1 ready

        // ---- layer 2: h2 = relu(h1 @ W2 + b2) ----
        #pragma unroll
        for (int ms = 0; ms < 2; ++ms) {
            const int row = ms * 16 + l16;
            bf16x8 A[8];
            #pragma unroll
            for (int ks = 0; ks < 8; ++ks) {
                const int koff = ks * 32 + lk * 8;
                A[ks] = *reinterpret_cast<const bf16x8*>(&h1[(row * 256 + koff) ^ ((row & 7) << 3)]);
            }
            #pragma unroll
            for (int ns = 0; ns < 2; ++ns) {
                f32x4 acc = {0.f, 0.f, 0.f, 0.f};
                #pragma unroll
                for (int ks = 0; ks < 8; ++ks)
                    acc = __builtin_amdgcn_mfma_f32_16x16x32_bf16(A[ks], B2[ns][ks], acc, 0, 0, 0);
                const int ccol = wcol + ns * 16 + l16;
                #pragma unroll
                for (int reg = 0; reg < 4; ++reg) {
                    const float v = fmaxf(acc[reg] + bias2[ns], 0.f);
                    const int rr = ms * 16 + lk * 4 + reg;   // C row = (lane>>4)*4+reg
                    h2[(rr * 256 + ccol) ^ ((rr & 7) << 3)] = (__bf16)v;
                }
            }
        }
        __syncthreads();   // h2 ready (h1 rewrite gated by next-iter barrier)

        // ---- layer 3: rel = relu(h2 @ W3 + b3); colsum += rel ----
        #pragma unroll
        for (int ms = 0; ms < 2; ++ms) {
            const int row = ms * 16 + l16;
            bf16x8 A[8];
            #pragma unroll
            for (int ks = 0; ks < 8; ++ks) {
                const int koff = ks * 32 + lk * 8;
                A[ks] = *reinterpret_cast<const bf16x8*>(&h2[(row * 256 + koff) ^ ((row & 7) << 3)]);
            }
            #pragma unroll
            for (int ns = 0; ns < 2; ++ns) {
                f32x4 acc = {0.f, 0.f, 0.f, 0.f};
                #pragma unroll
                for (int ks = 0; ks < 8; ++ks)
                    acc = __builtin_amdgcn_mfma_f32_16x16x32_bf16(A[ks], B3[ns][ks], acc, 0, 0, 0);
                float s = 0.f;
                #pragma unroll
                for (int reg = 0; reg < 4; ++reg)
                    s += fmaxf(acc[reg] + bias3[ns], 0.f);
                colsum[ns] += s;
            }
        }
    }

    // ---- reduce colsums across the 4 row-groups, one atomic per col ----
    #pragma unroll
    for (int ns = 0; ns < 2; ++ns) {
        float v = colsum[ns];
        v += __shfl_xor(v, 16, 64);
        v += __shfl_xor(v, 32, 64);
        if (lane < 16) atomicAdd(&emb[wcol + ns * 16 + l16], v);
    }

    // ---- last-block ticket: the final block runs the f-MLP ----
    __syncthreads();
    if (t == 0) {
        __threadfence();
        const unsigned int done = atomicAdd(ticket, 1u);
        is_last_s = (done == 511u);
    }
    __syncthreads();
    if (!is_last_s) return;

    __threadfence();   // acquire: make all blocks' emb atomics visible
    if (t < 256) fe[t] = emb[t];
    __syncthreads();
    // f1: 256 cols x 2-way k-split (128 each)
    {
        const int col = t & 255, ks = t >> 8;
        float acc = 0.f;
        #pragma unroll 8
        for (int k = ks * 128; k < ks * 128 + 128; ++k) acc = fmaf(fe[k], fW1[k * 256 + col], acc);
        fred[ks * 256 + col] = acc;
    }
    __syncthreads();
    if (t < 256) fy1[t] = fmaxf(fred[t] + fred[256 + t] + fb1[t], 0.f);
    __syncthreads();
    // f2: 512 cols x 1 thread each
    {
        float acc = fb2[t];
        #pragma unroll 8
        for (int k = 0; k < 256; ++k) acc = fmaf(fy1[k], fW2[k * 512 + t], acc);
        fy2[t] = fmaxf(acc, 0.f);
    }
    __syncthreads();
    // f3: 159 cols x 2-way k-split (256 each)
    {
        const int col = t & 255, ks = t >> 8;
        if (col < 159) {
            float acc = 0.f;
            #pragma unroll 8
            for (int k = ks * 256; k < ks * 256 + 256; ++k) acc = fmaf(fy2[k], fW3[k * 159 + col], acc);
            fred[ks * 256 + col] = acc;
        }
    }
    __syncthreads();
    if (t < 159) out[t] = fred[t] + fred[256 + t] + fb3[t];
}

// ---------------------------------------------------------------------------
extern "C" void kernel_launch(void* const* d_in, const int* in_sizes, int n_in,
                              void* d_out, int out_size, void* d_ws, size_t ws_size,
                              hipStream_t stream)
{
    const float* x   = (const float*)d_in[0];
    const float* q   = (const float*)d_in[1];
    const float* gW1 = (const float*)d_in[2];
    const float* gb1 = (const float*)d_in[3];
    const float* gW2 = (const float*)d_in[4];
    const float* gb2 = (const float*)d_in[5];
    const float* gW3 = (const float*)d_in[6];
    const float* gb3 = (const float*)d_in[7];
    const float* fW1 = (const float*)d_in[8];
    const float* fb1 = (const float*)d_in[9];
    const float* fW2 = (const float*)d_in[10];
    const float* fb2 = (const float*)d_in[11];
    const float* fW3 = (const float*)d_in[12];
    const float* fb3 = (const float*)d_in[13];
    float* out = (float*)d_out;

    char* ws = (char*)d_ws;
    float* a_  = (float*)(ws);                                  // 512KB
    float* b_  = (float*)(ws + 512 * 1024);                     // 512KB
    float* cc  = (float*)(ws + 1024 * 1024);                    // 1KB
    float* emb = (float*)(ws + 1024 * 1024 + 1024);             // 1KB
    unsigned int* ticket = (unsigned int*)(ws + 1024 * 1024 + 2048);
    unsigned short* w2t = (unsigned short*)(ws + 1024 * 1024 + 4096);              // 128KB
    unsigned short* w3t = (unsigned short*)(ws + 1024 * 1024 + 4096 + 128 * 1024); // 128KB

    prep_all<<<289, 256, 0, stream>>>(x, q, gW1, gb1, gW2, gW3, a_, b_, cc, emb,
                                      ticket, w2t, w3t);
    rn_main<<<512, 512, 0, stream>>>(a_, b_, cc, w2t, w3t, gb2, gb3, emb, ticket,
                                     fW1, fb1, fW2, fb2, fW3, fb3, out);
}